// Round 1
// baseline (297.329 us; speedup 1.0000x reference)
//
#include <hip/hip_runtime.h>
#include <hip/hip_bf16.h>
#include <math.h>

// SwitchMoE: B=16,T=4096,D=256,H=512,E=8, top-2 routing.
// Sparse (top-2 only) bf16-MFMA implementation, fp64 gating for tie-exactness.

#define N_TOK 65536
#define D_DIM 256
#define H_DIM 512
#define E_NUM 8

typedef __bf16 bf16x8 __attribute__((ext_vector_type(8)));
typedef float f32x4 __attribute__((ext_vector_type(4)));

static __device__ __forceinline__ ushort f2bf(float f) {
    __hip_bfloat16 h = __float2bfloat16(f);  // RNE
    ushort u;
    __builtin_memcpy(&u, &h, 2);
    return u;
}

// ---------------------------------------------------------------------------
// Pack W1/W2 fp32 -> bf16 in MFMA-B-fragment-major layout.
// W1p: [e][nb=H/16][kb=D/32][lane=64][j=8]  (value = W1[e][kb*32+(l>>4)*8+j][nb*16+(l&15)])
// W2p: [e][nb=D/16][kb=H/32][lane=64][j=8]
// ---------------------------------------------------------------------------
__global__ __launch_bounds__(256) void pack_w(const float* __restrict__ W1,
                                              const float* __restrict__ W2,
                                              ushort* __restrict__ W1p,
                                              ushort* __restrict__ W2p) {
    const int t = blockIdx.x * 256 + threadIdx.x;   // 0..131071
    const int l = t & 63;
    const int lo = l & 15, hi = l >> 4;
    ushort v[8];
    if (blockIdx.y == 0) {
        const int kb = (t >> 6) & 7;
        const int nb = (t >> 9) & 31;
        const int e  = t >> 14;
        const int k0 = kb * 32 + hi * 8;
        const int n  = nb * 16 + lo;
        const float* src = W1 + (size_t)e * D_DIM * H_DIM + n;
        #pragma unroll
        for (int j = 0; j < 8; ++j)
            v[j] = f2bf(src[(size_t)(k0 + j) * H_DIM]);
        *(uint4*)(W1p + (size_t)t * 8) = *(const uint4*)v;
    } else {
        const int kb = (t >> 6) & 15;
        const int nb = (t >> 10) & 15;
        const int e  = t >> 14;
        const int k0 = kb * 32 + hi * 8;
        const int n  = nb * 16 + lo;
        const float* src = W2 + (size_t)e * H_DIM * D_DIM + n;
        #pragma unroll
        for (int j = 0; j < 8; ++j)
            v[j] = f2bf(src[(size_t)(k0 + j) * D_DIM]);
        *(uint4*)(W2p + (size_t)t * 8) = *(const uint4*)v;
    }
}

// ---------------------------------------------------------------------------
// Gating: convert x -> bf16 (ws), fp64 logits, softmax, top-2, expert lists.
// Block = 256 threads handles 64 tokens (4 threads/token).
// ---------------------------------------------------------------------------
__global__ __launch_bounds__(256) void gating(const float* __restrict__ x,
                                              const float* __restrict__ gate_w,
                                              const float* __restrict__ gate_b,
                                              ushort* __restrict__ xb,
                                              int* __restrict__ counts,
                                              int* __restrict__ idx_list,
                                              float* __restrict__ wt_list) {
    __shared__ __align__(16) float xt[64 * 256];
    __shared__ float gws[256 * 8];
    __shared__ int lc[8];
    __shared__ int lbase[8];

    const int tid = threadIdx.x;
    const size_t t0 = (size_t)blockIdx.x * 64;

    for (int i = tid; i < 2048; i += 256) gws[i] = gate_w[i];
    if (tid < 8) lc[tid] = 0;

    const float4* xs4 = (const float4*)(x + t0 * D_DIM);
    ushort* xbo = xb + t0 * D_DIM;
    #pragma unroll
    for (int it = 0; it < 16; ++it) {
        const int idx = tid + it * 256;          // 0..4095
        const float4 v = xs4[idx];
        *(float4*)&xt[idx * 4] = v;
        ushort4 bv;
        bv.x = f2bf(v.x); bv.y = f2bf(v.y); bv.z = f2bf(v.z); bv.w = f2bf(v.w);
        *(ushort4*)(xbo + idx * 4) = bv;
    }
    __syncthreads();

    const int m = tid >> 2, q = tid & 3;
    double lg[8] = {0, 0, 0, 0, 0, 0, 0, 0};
    const float* xr = &xt[m * 256 + q * 64];
    for (int k = 0; k < 64; ++k) {
        const double xv = (double)xr[k];
        const float* g = &gws[(q * 64 + k) * 8];
        #pragma unroll
        for (int e2 = 0; e2 < 8; ++e2) lg[e2] += xv * (double)g[e2];
    }
    #pragma unroll
    for (int e2 = 0; e2 < 8; ++e2) {
        lg[e2] += __shfl_xor(lg[e2], 1, 64);
        lg[e2] += __shfl_xor(lg[e2], 2, 64);
    }

    int e0 = 0, e1 = 0, lp0 = 0, lp1 = 0;
    float p0 = 0.f, p1 = 0.f;
    if (q == 0) {
        #pragma unroll
        for (int e2 = 0; e2 < 8; ++e2) lg[e2] += (double)gate_b[e2];
        double b0 = -1e300, b1v = -1e300;
        #pragma unroll
        for (int e2 = 0; e2 < 8; ++e2)
            if (lg[e2] > b0) { b0 = lg[e2]; e0 = e2; }
        e1 = -1;
        #pragma unroll
        for (int e2 = 0; e2 < 8; ++e2)
            if (e2 != e0 && lg[e2] > b1v) { b1v = lg[e2]; e1 = e2; }
        double s = 0;
        #pragma unroll
        for (int e2 = 0; e2 < 8; ++e2) s += exp(lg[e2] - b0);
        p0 = (float)(1.0 / s);
        p1 = (float)(exp(b1v - b0) / s);
        lp0 = atomicAdd(&lc[e0], 1);
        lp1 = atomicAdd(&lc[e1], 1);
    }
    __syncthreads();
    if (tid < 8) lbase[tid] = atomicAdd(&counts[tid], lc[tid]);
    __syncthreads();
    if (q == 0) {
        const int tok = (int)t0 + m;
        const int o0 = e0 * N_TOK + lbase[e0] + lp0;
        idx_list[o0] = tok; wt_list[o0] = p0;
        const int o1 = e1 * N_TOK + lbase[e1] + lp1;
        idx_list[o1] = tok; wt_list[o1] = p1;
    }
}

// ---------------------------------------------------------------------------
// Expert kernel: 64-row tiles of one expert's token list.
// 512 threads (8 waves). GEMM1: X[64,256]@W1[256,512] -> gelu -> H (LDS bf16)
// GEMM2: H[64,512]@W2[512,256] -> (y+b2)*wt atomicAdd to out.
// LDS rows XOR-swizzled: byte ^= (row&7)<<4 (16B granularity).
// ---------------------------------------------------------------------------
__global__ __launch_bounds__(512) void moe_expert(const ushort* __restrict__ xb,
                                                  const ushort* __restrict__ W1p,
                                                  const ushort* __restrict__ W2p,
                                                  const float* __restrict__ b1,
                                                  const float* __restrict__ b2,
                                                  const int* __restrict__ counts,
                                                  const int* __restrict__ idx_list,
                                                  const float* __restrict__ wt_list,
                                                  float* __restrict__ out) {
    __shared__ __align__(16) char Xs[64 * 512];    // [64 rows][512B] swizzled
    __shared__ __align__(16) char Hs[64 * 1024];   // [64 rows][1024B] swizzled
    __shared__ int toks[64];
    __shared__ float wts[64];

    const int e = blockIdx.y;
    const int cnt = counts[e];
    const int row0 = blockIdx.x * 64;
    if (row0 >= cnt) return;
    const int nval = min(64, cnt - row0);
    const int tid = threadIdx.x;

    if (tid < 64) {
        const bool vld = tid < nval;
        toks[tid] = vld ? idx_list[e * N_TOK + row0 + tid] : 0;
        wts[tid]  = vld ? wt_list[e * N_TOK + row0 + tid] : 0.0f;
    }
    __syncthreads();

    // --- stage gathered X rows (bf16) into swizzled LDS ---
    {
        const int r = tid >> 3, s = tid & 7;      // 8 threads/row, 64B each
        const char* src = (const char*)(xb + (size_t)toks[r] * D_DIM);
        char* dst = Xs + r * 512;
        const int sw = (r & 7) << 4;
        #pragma unroll
        for (int c = 0; c < 4; ++c) {
            const int bo = s * 64 + c * 16;
            *(uint4*)(dst + (bo ^ sw)) = *(const uint4*)(src + bo);
        }
    }
    __syncthreads();

    const int w = tid >> 6;          // wave 0..7
    const int l = tid & 63;
    const int lo = l & 15, hi = l >> 4;

    // --- GEMM1: wave w computes H cols [w*64, w*64+64) ---
    f32x4 acc[4][4];
    #pragma unroll
    for (int mi = 0; mi < 4; ++mi)
        #pragma unroll
        for (int ni = 0; ni < 4; ++ni)
            acc[mi][ni] = (f32x4){0.f, 0.f, 0.f, 0.f};

    const char* w1b = (const char*)(W1p + (size_t)(e * 32 + w * 4) * 8 * 512 + l * 8);
    #pragma unroll 2
    for (int ks = 0; ks < 8; ++ks) {
        bf16x8 af[4];
        #pragma unroll
        for (int mi = 0; mi < 4; ++mi) {
            const int m = mi * 16 + lo;
            af[mi] = *(const bf16x8*)(Xs + m * 512 + ((ks * 64 + hi * 16) ^ ((m & 7) << 4)));
        }
        bf16x8 bfr[4];
        #pragma unroll
        for (int ni = 0; ni < 4; ++ni)
            bfr[ni] = *(const bf16x8*)(w1b + (size_t)(ni * 8 + ks) * 1024);
        #pragma unroll
        for (int mi = 0; mi < 4; ++mi)
            #pragma unroll
            for (int ni = 0; ni < 4; ++ni)
                acc[mi][ni] = __builtin_amdgcn_mfma_f32_16x16x32_bf16(af[mi], bfr[ni], acc[mi][ni], 0, 0, 0);
    }

    // --- bias + exact-erf GeLU -> bf16 H in swizzled LDS ---
    #pragma unroll
    for (int ni = 0; ni < 4; ++ni) {
        const int col = w * 64 + ni * 16 + lo;
        const float b1v = b1[e * H_DIM + col];
        #pragma unroll
        for (int mi = 0; mi < 4; ++mi) {
            #pragma unroll
            for (int rg = 0; rg < 4; ++rg) {
                const int r = mi * 16 + hi * 4 + rg;
                const float v = acc[mi][ni][rg] + b1v;
                const float g = 0.5f * v * (1.0f + erff(v * 0.70710678118654752f));
                *(ushort*)(Hs + r * 1024 + ((col * 2) ^ ((r & 7) << 4))) = f2bf(g);
            }
        }
    }
    __syncthreads();

    // --- GEMM2: wave w computes Y cols [w*32, w*32+32), full K=512 ---
    f32x4 acc2[4][2];
    #pragma unroll
    for (int mi = 0; mi < 4; ++mi)
        #pragma unroll
        for (int ni = 0; ni < 2; ++ni)
            acc2[mi][ni] = (f32x4){0.f, 0.f, 0.f, 0.f};

    const char* w2b = (const char*)(W2p + (size_t)(e * 16 + w * 2) * 16 * 512 + l * 8);
    #pragma unroll 2
    for (int ks = 0; ks < 16; ++ks) {
        bf16x8 af[4];
        #pragma unroll
        for (int mi = 0; mi < 4; ++mi) {
            const int m = mi * 16 + lo;
            af[mi] = *(const bf16x8*)(Hs + m * 1024 + ((ks * 64 + hi * 16) ^ ((m & 7) << 4)));
        }
        bf16x8 bfr[2];
        #pragma unroll
        for (int ni = 0; ni < 2; ++ni)
            bfr[ni] = *(const bf16x8*)(w2b + (size_t)(ni * 16 + ks) * 1024);
        #pragma unroll
        for (int mi = 0; mi < 4; ++mi)
            #pragma unroll
            for (int ni = 0; ni < 2; ++ni)
                acc2[mi][ni] = __builtin_amdgcn_mfma_f32_16x16x32_bf16(af[mi], bfr[ni], acc2[mi][ni], 0, 0, 0);
    }

    // --- epilogue: (y + b2) * weight, atomicAdd into out ---
    #pragma unroll
    for (int ni = 0; ni < 2; ++ni) {
        const int col = w * 32 + ni * 16 + lo;
        const float b2v = b2[e * D_DIM + col];
        #pragma unroll
        for (int mi = 0; mi < 4; ++mi) {
            #pragma unroll
            for (int rg = 0; rg < 4; ++rg) {
                const int r = mi * 16 + hi * 4 + rg;
                if (r < nval) {
                    const float v = (acc2[mi][ni][rg] + b2v) * wts[r];
                    atomicAdd(&out[(size_t)toks[r] * D_DIM + col], v);
                }
            }
        }
    }
}

// ---------------------------------------------------------------------------
extern "C" void kernel_launch(void* const* d_in, const int* in_sizes, int n_in,
                              void* d_out, int out_size, void* d_ws, size_t ws_size,
                              hipStream_t stream) {
    const float* x      = (const float*)d_in[0];
    const float* gate_w = (const float*)d_in[1];
    const float* gate_b = (const float*)d_in[2];
    const float* W1     = (const float*)d_in[3];
    const float* b1     = (const float*)d_in[4];
    const float* W2     = (const float*)d_in[5];
    const float* b2     = (const float*)d_in[6];
    float* out = (float*)d_out;

    char* ws = (char*)d_ws;
    ushort* xb      = (ushort*)(ws);                        // 33,554,432 B
    ushort* W1p     = (ushort*)(ws + 33554432);             //  2,097,152 B
    ushort* W2p     = (ushort*)(ws + 35651584);             //  2,097,152 B
    int*    idx_lst = (int*)   (ws + 37748736);             //  2,097,152 B
    float*  wt_lst  = (float*) (ws + 39845888);             //  2,097,152 B
    int*    counts  = (int*)   (ws + 41943040);             //         32 B

    hipMemsetAsync(counts, 0, 32, stream);
    hipMemsetAsync(d_out, 0, (size_t)out_size * sizeof(float), stream);

    pack_w<<<dim3(512, 2), 256, 0, stream>>>(W1, W2, W1p, W2p);
    gating<<<dim3(1024), 256, 0, stream>>>(x, gate_w, gate_b, xb, counts, idx_lst, wt_lst);
    moe_expert<<<dim3(1024, E_NUM), 512, 0, stream>>>(xb, W1p, W2p, b1, b2, counts,
                                                      idx_lst, wt_lst, out);
}

// Round 2
// 232.764 us; speedup vs baseline: 1.2774x; 1.2774x over previous
//
#include <hip/hip_runtime.h>
#include <hip/hip_bf16.h>
#include <math.h>

// SwitchMoE: B=16,T=4096,D=256,H=512,E=8, top-2 routing.
// Sparse (top-2 only) bf16-MFMA implementation, fp64 gating for tie-exactness.

#define N_TOK 65536
#define D_DIM 256
#define H_DIM 512
#define E_NUM 8
#define GRID_TILES 2080   // >= max tiles (2048+7), multiple of 8 for XCD swizzle

typedef __bf16 bf16x8 __attribute__((ext_vector_type(8)));
typedef float f32x4 __attribute__((ext_vector_type(4)));

static __device__ __forceinline__ ushort f2bf(float f) {
    __hip_bfloat16 h = __float2bfloat16(f);  // RNE
    ushort u;
    __builtin_memcpy(&u, &h, 2);
    return u;
}

// Branch-free GeLU, exact-erf via Abramowitz-Stegun 7.1.26 (|err|<=1.5e-7).
static __device__ __forceinline__ float gelu(float v) {
    const float a = fabsf(v) * 0.70710678118654752f;
    const float t = 1.0f / (1.0f + 0.3275911f * a);
    const float p = t * (0.254829592f + t * (-0.284496736f + t * (1.421413741f +
                    t * (-1.453152027f + t * 1.061405429f))));
    float er = 1.0f - p * __expf(-a * a);
    er = copysignf(er, v);
    return 0.5f * v * (1.0f + er);
}

// ---------------------------------------------------------------------------
// Pack W1/W2 fp32 -> bf16 in MFMA-B-fragment-major layout.
// W1p: [e][nb=H/16][kb=D/32][lane=64][j=8]  (value = W1[e][kb*32+(l>>4)*8+j][nb*16+(l&15)])
// W2p: [e][nb=D/16][kb=H/32][lane=64][j=8]
// ---------------------------------------------------------------------------
__global__ __launch_bounds__(256) void pack_w(const float* __restrict__ W1,
                                              const float* __restrict__ W2,
                                              ushort* __restrict__ W1p,
                                              ushort* __restrict__ W2p) {
    const int t = blockIdx.x * 256 + threadIdx.x;   // 0..131071
    const int l = t & 63;
    const int lo = l & 15, hi = l >> 4;
    ushort v[8];
    if (blockIdx.y == 0) {
        const int kb = (t >> 6) & 7;
        const int nb = (t >> 9) & 31;
        const int e  = t >> 14;
        const int k0 = kb * 32 + hi * 8;
        const int n  = nb * 16 + lo;
        const float* src = W1 + (size_t)e * D_DIM * H_DIM + n;
        #pragma unroll
        for (int j = 0; j < 8; ++j)
            v[j] = f2bf(src[(size_t)(k0 + j) * H_DIM]);
        *(uint4*)(W1p + (size_t)t * 8) = *(const uint4*)v;
    } else {
        const int kb = (t >> 6) & 15;
        const int nb = (t >> 10) & 15;
        const int e  = t >> 14;
        const int k0 = kb * 32 + hi * 8;
        const int n  = nb * 16 + lo;
        const float* src = W2 + (size_t)e * H_DIM * D_DIM + n;
        #pragma unroll
        for (int j = 0; j < 8; ++j)
            v[j] = f2bf(src[(size_t)(k0 + j) * D_DIM]);
        *(uint4*)(W2p + (size_t)t * 8) = *(const uint4*)v;
    }
}

// ---------------------------------------------------------------------------
// Gating: convert x -> bf16 (ws), fp64 logits, softmax, top-2, expert lists.
// Block = 256 threads handles 64 tokens (4 threads/token).
// xt padded to 260 floats/row: row stride 1040B != 0 mod 128 -> no 64-way
// bank conflict on the dot-product reads (was the gating bottleneck).
// ---------------------------------------------------------------------------
__global__ __launch_bounds__(256) void gating(const float* __restrict__ x,
                                              const float* __restrict__ gate_w,
                                              const float* __restrict__ gate_b,
                                              ushort* __restrict__ xb,
                                              int* __restrict__ counts,
                                              int* __restrict__ idx_list,
                                              float* __restrict__ wt_list) {
    __shared__ __align__(16) float xt[64 * 260];
    __shared__ float gws[256 * 8];
    __shared__ int lc[8];
    __shared__ int lbase[8];

    const int tid = threadIdx.x;
    const size_t t0 = (size_t)blockIdx.x * 64;

    for (int i = tid; i < 2048; i += 256) gws[i] = gate_w[i];
    if (tid < 8) lc[tid] = 0;

    const float4* xs4 = (const float4*)(x + t0 * D_DIM);
    ushort* xbo = xb + t0 * D_DIM;
    #pragma unroll
    for (int it = 0; it < 16; ++it) {
        const int idx = tid + it * 256;          // 0..4095 (float4 units)
        const float4 v = xs4[idx];
        const int tok = idx >> 6, dc = idx & 63;
        *(float4*)&xt[tok * 260 + dc * 4] = v;
        ushort4 bv;
        bv.x = f2bf(v.x); bv.y = f2bf(v.y); bv.z = f2bf(v.z); bv.w = f2bf(v.w);
        *(ushort4*)(xbo + idx * 4) = bv;
    }
    __syncthreads();

    const int m = tid >> 2, q = tid & 3;
    double lg[8] = {0, 0, 0, 0, 0, 0, 0, 0};
    const float* xr = &xt[m * 260 + q * 64];
    for (int k = 0; k < 64; ++k) {
        const double xv = (double)xr[k];
        const float* g = &gws[(q * 64 + k) * 8];
        #pragma unroll
        for (int e2 = 0; e2 < 8; ++e2) lg[e2] += xv * (double)g[e2];
    }
    #pragma unroll
    for (int e2 = 0; e2 < 8; ++e2) {
        lg[e2] += __shfl_xor(lg[e2], 1, 64);
        lg[e2] += __shfl_xor(lg[e2], 2, 64);
    }

    int e0 = 0, e1 = 0, lp0 = 0, lp1 = 0;
    float p0 = 0.f, p1 = 0.f;
    if (q == 0) {
        #pragma unroll
        for (int e2 = 0; e2 < 8; ++e2) lg[e2] += (double)gate_b[e2];
        double b0 = -1e300, b1v = -1e300;
        #pragma unroll
        for (int e2 = 0; e2 < 8; ++e2)
            if (lg[e2] > b0) { b0 = lg[e2]; e0 = e2; }
        e1 = -1;
        #pragma unroll
        for (int e2 = 0; e2 < 8; ++e2)
            if (e2 != e0 && lg[e2] > b1v) { b1v = lg[e2]; e1 = e2; }
        double s = 0;
        #pragma unroll
        for (int e2 = 0; e2 < 8; ++e2) s += exp(lg[e2] - b0);
        p0 = (float)(1.0 / s);
        p1 = (float)(exp(b1v - b0) / s);
        lp0 = atomicAdd(&lc[e0], 1);
        lp1 = atomicAdd(&lc[e1], 1);
    }
    __syncthreads();
    if (tid < 8) lbase[tid] = atomicAdd(&counts[tid], lc[tid]);
    __syncthreads();
    if (q == 0) {
        const int tok = (int)t0 + m;
        const int o0 = e0 * N_TOK + lbase[e0] + lp0;
        idx_list[o0] = tok; wt_list[o0] = p0;
        const int o1 = e1 * N_TOK + lbase[e1] + lp1;
        idx_list[o1] = tok; wt_list[o1] = p1;
    }
}

// ---------------------------------------------------------------------------
// Build exact tile list (expert-ordered): desc = (e<<28)|row0. One block.
// ---------------------------------------------------------------------------
__global__ __launch_bounds__(256) void make_tiles(const int* __restrict__ counts,
                                                  int* __restrict__ tiles,
                                                  int* __restrict__ n_tiles) {
    __shared__ int base[9];
    if (threadIdx.x == 0) {
        int s = 0;
        #pragma unroll
        for (int e = 0; e < 8; ++e) { base[e] = s; s += (counts[e] + 63) >> 6; }
        base[8] = s;
        *n_tiles = s;
    }
    __syncthreads();
    for (int e = 0; e < 8; ++e) {
        const int nt = base[e + 1] - base[e];
        for (int i = threadIdx.x; i < nt; i += 256)
            tiles[base[e] + i] = (e << 28) | (i << 6);
    }
}

// ---------------------------------------------------------------------------
// Expert kernel: one 64-row tile per block, from the exact tile list.
// 512 threads (8 waves). GEMM1: X[64,256]@W1[256,512] -> gelu -> H (LDS bf16)
// GEMM2: H[64,512]@W2[512,256] -> (y+b2)*wt atomicAdd to out.
// Xs (32KB) overlaid inside Hs (64KB) union -> LDS ~66KB -> 2 blocks/CU.
// XCD-chunk swizzle: expert-ordered tiles land chunked per XCD -> W L2-local.
// LDS rows XOR-swizzled: byte ^= (row&7)<<4 (16B granularity).
// ---------------------------------------------------------------------------
__global__ __launch_bounds__(512, 4) void moe_expert(const ushort* __restrict__ xb,
                                                     const ushort* __restrict__ W1p,
                                                     const ushort* __restrict__ W2p,
                                                     const float* __restrict__ b1,
                                                     const float* __restrict__ b2,
                                                     const int* __restrict__ counts,
                                                     const int* __restrict__ idx_list,
                                                     const float* __restrict__ wt_list,
                                                     const int* __restrict__ tiles,
                                                     const int* __restrict__ n_tiles,
                                                     float* __restrict__ out) {
    __shared__ __align__(16) char U[65536];        // Hs[64][1024B]; Xs[64][512B] overlaid
    __shared__ int toks[64];
    __shared__ float wts[64];

    const int bid = blockIdx.x;
    const int wg = (bid & 7) * (GRID_TILES / 8) + (bid >> 3);   // bijective XCD chunking
    if (wg >= *n_tiles) return;
    const int desc = tiles[wg];
    const int e = desc >> 28;
    const int row0 = desc & 0x0FFFFFFF;
    const int cnt = counts[e];
    const int nval = min(64, cnt - row0);
    const int tid = threadIdx.x;

    char* Xs = U;
    char* Hs = U;

    if (tid < 64) {
        const bool vld = tid < nval;
        toks[tid] = vld ? idx_list[e * N_TOK + row0 + tid] : 0;
        wts[tid]  = vld ? wt_list[e * N_TOK + row0 + tid] : 0.0f;
    }
    __syncthreads();

    // --- stage gathered X rows (bf16) into swizzled LDS ---
    {
        const int r = tid >> 3, s = tid & 7;      // 8 threads/row, 64B each
        const char* src = (const char*)(xb + (size_t)toks[r] * D_DIM);
        char* dst = Xs + r * 512;
        const int sw = (r & 7) << 4;
        #pragma unroll
        for (int c = 0; c < 4; ++c) {
            const int bo = s * 64 + c * 16;
            *(uint4*)(dst + (bo ^ sw)) = *(const uint4*)(src + bo);
        }
    }
    __syncthreads();

    const int w = tid >> 6;          // wave 0..7
    const int l = tid & 63;
    const int lo = l & 15, hi = l >> 4;

    // --- GEMM1: wave w computes H cols [w*64, w*64+64) ---
    f32x4 acc[4][4];
    #pragma unroll
    for (int mi = 0; mi < 4; ++mi)
        #pragma unroll
        for (int ni = 0; ni < 4; ++ni)
            acc[mi][ni] = (f32x4){0.f, 0.f, 0.f, 0.f};

    const char* w1b = (const char*)(W1p + (size_t)(e * 32 + w * 4) * 8 * 512 + l * 8);
    #pragma unroll 4
    for (int ks = 0; ks < 8; ++ks) {
        bf16x8 af[4];
        #pragma unroll
        for (int mi = 0; mi < 4; ++mi) {
            const int m = mi * 16 + lo;
            af[mi] = *(const bf16x8*)(Xs + m * 512 + ((ks * 64 + hi * 16) ^ ((m & 7) << 4)));
        }
        bf16x8 bfr[4];
        #pragma unroll
        for (int ni = 0; ni < 4; ++ni)
            bfr[ni] = *(const bf16x8*)(w1b + (size_t)(ni * 8 + ks) * 1024);
        #pragma unroll
        for (int mi = 0; mi < 4; ++mi)
            #pragma unroll
            for (int ni = 0; ni < 4; ++ni)
                acc[mi][ni] = __builtin_amdgcn_mfma_f32_16x16x32_bf16(af[mi], bfr[ni], acc[mi][ni], 0, 0, 0);
    }

    __syncthreads();   // all waves done reading Xs before H overwrites the union

    // --- bias + GeLU -> bf16 H in swizzled LDS ---
    #pragma unroll
    for (int ni = 0; ni < 4; ++ni) {
        const int col = w * 64 + ni * 16 + lo;
        const float b1v = b1[e * H_DIM + col];
        #pragma unroll
        for (int mi = 0; mi < 4; ++mi) {
            #pragma unroll
            for (int rg = 0; rg < 4; ++rg) {
                const int r = mi * 16 + hi * 4 + rg;
                const float g = gelu(acc[mi][ni][rg] + b1v);
                *(ushort*)(Hs + r * 1024 + ((col * 2) ^ ((r & 7) << 4))) = f2bf(g);
            }
        }
    }
    __syncthreads();

    // --- GEMM2: wave w computes Y cols [w*32, w*32+32), full K=512 ---
    f32x4 acc2[4][2];
    #pragma unroll
    for (int mi = 0; mi < 4; ++mi)
        #pragma unroll
        for (int ni = 0; ni < 2; ++ni)
            acc2[mi][ni] = (f32x4){0.f, 0.f, 0.f, 0.f};

    const char* w2b = (const char*)(W2p + (size_t)(e * 16 + w * 2) * 16 * 512 + l * 8);
    #pragma unroll 4
    for (int ks = 0; ks < 16; ++ks) {
        bf16x8 af[4];
        #pragma unroll
        for (int mi = 0; mi < 4; ++mi) {
            const int m = mi * 16 + lo;
            af[mi] = *(const bf16x8*)(Hs + m * 1024 + ((ks * 64 + hi * 16) ^ ((m & 7) << 4)));
        }
        bf16x8 bfr[2];
        #pragma unroll
        for (int ni = 0; ni < 2; ++ni)
            bfr[ni] = *(const bf16x8*)(w2b + (size_t)(ni * 16 + ks) * 1024);
        #pragma unroll
        for (int mi = 0; mi < 4; ++mi)
            #pragma unroll
            for (int ni = 0; ni < 2; ++ni)
                acc2[mi][ni] = __builtin_amdgcn_mfma_f32_16x16x32_bf16(af[mi], bfr[ni], acc2[mi][ni], 0, 0, 0);
    }

    // --- epilogue: (y + b2) * weight, atomicAdd into out ---
    #pragma unroll
    for (int ni = 0; ni < 2; ++ni) {
        const int col = w * 32 + ni * 16 + lo;
        const float b2v = b2[e * D_DIM + col];
        #pragma unroll
        for (int mi = 0; mi < 4; ++mi) {
            #pragma unroll
            for (int rg = 0; rg < 4; ++rg) {
                const int r = mi * 16 + hi * 4 + rg;
                if (r < nval) {
                    const float v = (acc2[mi][ni][rg] + b2v) * wts[r];
                    atomicAdd(&out[(size_t)toks[r] * D_DIM + col], v);
                }
            }
        }
    }
}

// ---------------------------------------------------------------------------
extern "C" void kernel_launch(void* const* d_in, const int* in_sizes, int n_in,
                              void* d_out, int out_size, void* d_ws, size_t ws_size,
                              hipStream_t stream) {
    const float* x      = (const float*)d_in[0];
    const float* gate_w = (const float*)d_in[1];
    const float* gate_b = (const float*)d_in[2];
    const float* W1     = (const float*)d_in[3];
    const float* b1     = (const float*)d_in[4];
    const float* W2     = (const float*)d_in[5];
    const float* b2     = (const float*)d_in[6];
    float* out = (float*)d_out;

    char* ws = (char*)d_ws;
    ushort* xb      = (ushort*)(ws);                        // 33,554,432 B
    ushort* W1p     = (ushort*)(ws + 33554432);             //  2,097,152 B
    ushort* W2p     = (ushort*)(ws + 35651584);             //  2,097,152 B
    int*    idx_lst = (int*)   (ws + 37748736);             //  2,097,152 B
    float*  wt_lst  = (float*) (ws + 39845888);             //  2,097,152 B
    int*    counts  = (int*)   (ws + 41943040);             //         32 B
    int*    tiles   = (int*)   (ws + 41943104);             //      8,320 B
    int*    n_tiles = (int*)   (ws + 41951424);             //          4 B

    hipMemsetAsync(counts, 0, 32, stream);
    hipMemsetAsync(d_out, 0, (size_t)out_size * sizeof(float), stream);

    pack_w<<<dim3(512, 2), 256, 0, stream>>>(W1, W2, W1p, W2p);
    gating<<<dim3(1024), 256, 0, stream>>>(x, gate_w, gate_b, xb, counts, idx_lst, wt_lst);
    make_tiles<<<dim3(1), 256, 0, stream>>>(counts, tiles, n_tiles);
    moe_expert<<<dim3(GRID_TILES), 512, 0, stream>>>(xb, W1p, W2p, b1, b2, counts,
                                                     idx_lst, wt_lst, tiles, n_tiles, out);
}

// Round 3
// 228.118 us; speedup vs baseline: 1.3034x; 1.0204x over previous
//
#include <hip/hip_runtime.h>
#include <hip/hip_bf16.h>
#include <math.h>

// SwitchMoE: B=16,T=4096,D=256,H=512,E=8, top-2 routing.
// Sparse (top-2 only) bf16-MFMA implementation, fp64 gating for tie-exactness.

#define N_TOK 65536
#define D_DIM 256
#define H_DIM 512
#define E_NUM 8
#define GRID_TILES 2080   // >= max tiles (2048+7), multiple of 8 for XCD swizzle

typedef __bf16 bf16x8 __attribute__((ext_vector_type(8)));
typedef float f32x4 __attribute__((ext_vector_type(4)));

static __device__ __forceinline__ ushort f2bf(float f) {
    __hip_bfloat16 h = __float2bfloat16(f);  // RNE
    ushort u;
    __builtin_memcpy(&u, &h, 2);
    return u;
}

// Branch-free GeLU, exact-erf via A&S 7.1.26 3-term (|err|<=2.5e-5).
static __device__ __forceinline__ float gelu(float v) {
    const float a = fabsf(v) * 0.70710678118654752f;
    const float t = __builtin_amdgcn_rcpf(fmaf(a, 0.47047f, 1.0f));
    const float p = t * fmaf(t, fmaf(t, 0.7478556f, -0.0958798f), 0.3480242f);
    const float er = fmaf(-p, __expf(-a * a), 1.0f);   // erf(a), a>=0
    const float s = copysignf(er, v);
    return 0.5f * v * (1.0f + s);
}

// ---------------------------------------------------------------------------
// Pack W1/W2 fp32 -> bf16 in MFMA-fragment-major layout.
// W1p: [e][nb=H/16][kb=D/32][lane=64][j=8]  (value = W1[e][kb*32+(l>>4)*8+j][nb*16+(l&15)])
// W2p: [e][nb=D/16][kb=H/32][lane=64][j=8]
// (A and B fragments of 16x16x32 share this per-lane geometry.)
// ---------------------------------------------------------------------------
__global__ __launch_bounds__(256) void pack_w(const float* __restrict__ W1,
                                              const float* __restrict__ W2,
                                              ushort* __restrict__ W1p,
                                              ushort* __restrict__ W2p) {
    const int t = blockIdx.x * 256 + threadIdx.x;   // 0..131071
    const int l = t & 63;
    const int lo = l & 15, hi = l >> 4;
    ushort v[8];
    if (blockIdx.y == 0) {
        const int kb = (t >> 6) & 7;
        const int nb = (t >> 9) & 31;
        const int e  = t >> 14;
        const int k0 = kb * 32 + hi * 8;
        const int n  = nb * 16 + lo;
        const float* src = W1 + (size_t)e * D_DIM * H_DIM + n;
        #pragma unroll
        for (int j = 0; j < 8; ++j)
            v[j] = f2bf(src[(size_t)(k0 + j) * H_DIM]);
        *(uint4*)(W1p + (size_t)t * 8) = *(const uint4*)v;
    } else {
        const int kb = (t >> 6) & 15;
        const int nb = (t >> 10) & 15;
        const int e  = t >> 14;
        const int k0 = kb * 32 + hi * 8;
        const int n  = nb * 16 + lo;
        const float* src = W2 + (size_t)e * H_DIM * D_DIM + n;
        #pragma unroll
        for (int j = 0; j < 8; ++j)
            v[j] = f2bf(src[(size_t)(k0 + j) * D_DIM]);
        *(uint4*)(W2p + (size_t)t * 8) = *(const uint4*)v;
    }
}

// ---------------------------------------------------------------------------
// Gating: convert x -> bf16 (ws), fp64 logits, softmax, top-2, expert lists.
// 4 threads per token stream the token's quarter-row straight from global
// into the fp64 MAC (no LDS x tile -> 8.3KB LDS -> high occupancy).
// ---------------------------------------------------------------------------
__global__ __launch_bounds__(256) void gating(const float* __restrict__ x,
                                              const float* __restrict__ gate_w,
                                              const float* __restrict__ gate_b,
                                              ushort* __restrict__ xb,
                                              int* __restrict__ counts,
                                              int* __restrict__ idx_list,
                                              float* __restrict__ wt_list) {
    __shared__ float gws[2048];
    __shared__ int lc[8];
    __shared__ int lbase[8];

    const int tid = threadIdx.x;
    const size_t t0 = (size_t)blockIdx.x * 64;

    for (int i = tid; i < 2048; i += 256) gws[i] = gate_w[i];
    if (tid < 8) lc[tid] = 0;
    __syncthreads();

    const int m = tid >> 2, q = tid & 3;               // token m, quarter q
    const float4* xr = (const float4*)(x + (t0 + m) * D_DIM + q * 64);
    ushort4* xw = (ushort4*)(xb + (t0 + m) * D_DIM + q * 64);

    double lg[8] = {0, 0, 0, 0, 0, 0, 0, 0};
    #pragma unroll
    for (int it = 0; it < 16; ++it) {
        const float4 v = xr[it];
        ushort4 bv;
        bv.x = f2bf(v.x); bv.y = f2bf(v.y); bv.z = f2bf(v.z); bv.w = f2bf(v.w);
        xw[it] = bv;
        const float* g = &gws[(q * 64 + it * 4) * 8];
        const float vv[4] = {v.x, v.y, v.z, v.w};
        #pragma unroll
        for (int j = 0; j < 4; ++j) {
            const double xv = (double)vv[j];
            #pragma unroll
            for (int e2 = 0; e2 < 8; ++e2) lg[e2] += xv * (double)g[j * 8 + e2];
        }
    }
    #pragma unroll
    for (int e2 = 0; e2 < 8; ++e2) {
        lg[e2] += __shfl_xor(lg[e2], 1, 64);
        lg[e2] += __shfl_xor(lg[e2], 2, 64);
    }

    int e0 = 0, e1 = 0, lp0 = 0, lp1 = 0;
    float p0 = 0.f, p1 = 0.f;
    if (q == 0) {
        #pragma unroll
        for (int e2 = 0; e2 < 8; ++e2) lg[e2] += (double)gate_b[e2];
        double b0 = -1e300, b1v = -1e300;
        #pragma unroll
        for (int e2 = 0; e2 < 8; ++e2)
            if (lg[e2] > b0) { b0 = lg[e2]; e0 = e2; }
        e1 = -1;
        #pragma unroll
        for (int e2 = 0; e2 < 8; ++e2)
            if (e2 != e0 && lg[e2] > b1v) { b1v = lg[e2]; e1 = e2; }
        double s = 0;
        #pragma unroll
        for (int e2 = 0; e2 < 8; ++e2) s += exp(lg[e2] - b0);
        p0 = (float)(1.0 / s);
        p1 = (float)(exp(b1v - b0) / s);
        lp0 = atomicAdd(&lc[e0], 1);
        lp1 = atomicAdd(&lc[e1], 1);
    }
    __syncthreads();
    if (tid < 8) lbase[tid] = atomicAdd(&counts[tid], lc[tid]);
    __syncthreads();
    if (q == 0) {
        const int tok = (int)t0 + m;
        const int o0 = e0 * N_TOK + lbase[e0] + lp0;
        idx_list[o0] = tok; wt_list[o0] = p0;
        const int o1 = e1 * N_TOK + lbase[e1] + lp1;
        idx_list[o1] = tok; wt_list[o1] = p1;
    }
}

// ---------------------------------------------------------------------------
// Build exact tile list (expert-ordered): desc = (e<<28)|row0. One block.
// ---------------------------------------------------------------------------
__global__ __launch_bounds__(256) void make_tiles(const int* __restrict__ counts,
                                                  int* __restrict__ tiles,
                                                  int* __restrict__ n_tiles) {
    __shared__ int base[9];
    if (threadIdx.x == 0) {
        int s = 0;
        #pragma unroll
        for (int e = 0; e < 8; ++e) { base[e] = s; s += (counts[e] + 63) >> 6; }
        base[8] = s;
        *n_tiles = s;
    }
    __syncthreads();
    for (int e = 0; e < 8; ++e) {
        const int nt = base[e + 1] - base[e];
        for (int i = threadIdx.x; i < nt; i += 256)
            tiles[base[e] + i] = (e << 28) | (i << 6);
    }
}

// ---------------------------------------------------------------------------
// Expert kernel: one 64-row tile per block. 512 threads (8 waves).
// GEMM1 (operand-swapped: A=W1p, B=X): lane holds 4 consecutive hcols of one
//   token -> vectorized ds_write_b64 H stores.
// GEMM2: H[64,512]@W2[512,256] -> (y+b2)*wt atomicAdd to out.
// W fragments register-double-buffered (prefetch ks+1 before ks's MFMAs).
// Xs (32KB) overlaid inside Hs (64KB) union -> ~66KB LDS -> 2 blocks/CU.
// LDS rows XOR-swizzled: byte ^= (slot&7)<<4.
// ---------------------------------------------------------------------------
__global__ __launch_bounds__(512, 4) void moe_expert(const ushort* __restrict__ xb,
                                                     const ushort* __restrict__ W1p,
                                                     const ushort* __restrict__ W2p,
                                                     const float* __restrict__ b1,
                                                     const float* __restrict__ b2,
                                                     const int* __restrict__ counts,
                                                     const int* __restrict__ idx_list,
                                                     const float* __restrict__ wt_list,
                                                     const int* __restrict__ tiles,
                                                     const int* __restrict__ n_tiles,
                                                     float* __restrict__ out) {
    __shared__ __align__(16) char U[65536];        // Hs[64][1024B]; Xs[64][512B] overlaid
    __shared__ int toks[64];
    __shared__ float wts[64];

    const int bid = blockIdx.x;
    const int wg = (bid & 7) * (GRID_TILES / 8) + (bid >> 3);   // bijective XCD chunking
    if (wg >= *n_tiles) return;
    const int desc = tiles[wg];
    const int e = desc >> 28;
    const int row0 = desc & 0x0FFFFFFF;
    const int cnt = counts[e];
    const int nval = min(64, cnt - row0);
    const int tid = threadIdx.x;

    char* Xs = U;
    char* Hs = U;

    const int w = tid >> 6;          // wave 0..7
    const int l = tid & 63;
    const int lo = l & 15, hi = l >> 4;

    if (tid < 64) {
        const bool vld = tid < nval;
        toks[tid] = vld ? idx_list[e * N_TOK + row0 + tid] : 0;
        wts[tid]  = vld ? wt_list[e * N_TOK + row0 + tid] : 0.0f;
    }

    // --- prefetch W1 ks=0 fragments (independent of toks) ---
    const char* w1b = (const char*)W1p + (size_t)(e * 32 + w * 4) * 8192 + (size_t)l * 16;
    bf16x8 wf[2][4];
    #pragma unroll
    for (int nb = 0; nb < 4; ++nb)
        wf[0][nb] = *(const bf16x8*)(w1b + nb * 8192);

    __syncthreads();

    // --- stage gathered X rows (bf16) into swizzled LDS ---
    {
        const int r = tid >> 3, s = tid & 7;      // 8 threads/row, 64B each
        const char* src = (const char*)(xb + (size_t)toks[r] * D_DIM);
        char* dst = Xs + r * 512;
        const int sw = (r & 7) << 4;
        #pragma unroll
        for (int c = 0; c < 4; ++c) {
            const int bo = s * 64 + c * 16;
            *(uint4*)(dst + (bo ^ sw)) = *(const uint4*)(src + bo);
        }
    }
    __syncthreads();

    // --- GEMM1 (swapped): acc1[nb][tb] = sum_k W1[k][hcol] * X[tok][k] ---
    f32x4 acc1[4][4];
    #pragma unroll
    for (int nb = 0; nb < 4; ++nb)
        #pragma unroll
        for (int tb = 0; tb < 4; ++tb)
            acc1[nb][tb] = (f32x4){0.f, 0.f, 0.f, 0.f};

    #pragma unroll
    for (int ks = 0; ks < 8; ++ks) {
        const int cur = ks & 1, nxt = cur ^ 1;
        if (ks < 7) {
            #pragma unroll
            for (int nb = 0; nb < 4; ++nb)
                wf[nxt][nb] = *(const bf16x8*)(w1b + nb * 8192 + (ks + 1) * 1024);
        }
        #pragma unroll
        for (int tb = 0; tb < 4; ++tb) {
            const int slot = tb * 16 + lo;
            const bf16x8 xf = *(const bf16x8*)(Xs + slot * 512 +
                              ((ks * 64 + hi * 16) ^ ((slot & 7) << 4)));
            #pragma unroll
            for (int nb = 0; nb < 4; ++nb)
                acc1[nb][tb] = __builtin_amdgcn_mfma_f32_16x16x32_bf16(wf[cur][nb], xf, acc1[nb][tb], 0, 0, 0);
        }
    }

    // --- prefetch W2 ks=0 fragments before the GeLU phase ---
    const char* w2b = (const char*)W2p + (size_t)(e * 16 + w * 2) * 16384 + (size_t)l * 16;
    bf16x8 wf2[2][2];
    wf2[0][0] = *(const bf16x8*)(w2b);
    wf2[0][1] = *(const bf16x8*)(w2b + 16384);

    __syncthreads();   // all waves done reading Xs before H overwrites the union

    // --- bias + GeLU -> bf16 H (vectorized b64 stores, 4 hcols per lane) ---
    #pragma unroll
    for (int nb = 0; nb < 4; ++nb) {
        const int hc0 = w * 64 + nb * 16 + hi * 4;
        const float4 b1q = *(const float4*)(b1 + e * H_DIM + hc0);
        #pragma unroll
        for (int tb = 0; tb < 4; ++tb) {
            const int slot = tb * 16 + lo;
            ushort4 hv;
            hv.x = f2bf(gelu(acc1[nb][tb][0] + b1q.x));
            hv.y = f2bf(gelu(acc1[nb][tb][1] + b1q.y));
            hv.z = f2bf(gelu(acc1[nb][tb][2] + b1q.z));
            hv.w = f2bf(gelu(acc1[nb][tb][3] + b1q.w));
            *(ushort4*)(Hs + slot * 1024 + ((hc0 * 2) ^ ((slot & 7) << 4))) = hv;
        }
    }
    __syncthreads();

    // --- GEMM2: acc2[mi][ni], A=H rows, B=W2p, double-buffered W2 frags ---
    f32x4 acc2[4][2];
    #pragma unroll
    for (int mi = 0; mi < 4; ++mi)
        #pragma unroll
        for (int ni = 0; ni < 2; ++ni)
            acc2[mi][ni] = (f32x4){0.f, 0.f, 0.f, 0.f};

    #pragma unroll
    for (int ks = 0; ks < 16; ++ks) {
        const int cur = ks & 1, nxt = cur ^ 1;
        if (ks < 15) {
            wf2[nxt][0] = *(const bf16x8*)(w2b + (ks + 1) * 1024);
            wf2[nxt][1] = *(const bf16x8*)(w2b + 16384 + (ks + 1) * 1024);
        }
        #pragma unroll
        for (int mi = 0; mi < 4; ++mi) {
            const int slot = mi * 16 + lo;
            const bf16x8 hf = *(const bf16x8*)(Hs + slot * 1024 +
                              ((ks * 64 + hi * 16) ^ ((slot & 7) << 4)));
            #pragma unroll
            for (int ni = 0; ni < 2; ++ni)
                acc2[mi][ni] = __builtin_amdgcn_mfma_f32_16x16x32_bf16(hf, wf2[cur][ni], acc2[mi][ni], 0, 0, 0);
        }
    }

    // --- epilogue: (y + b2) * weight, atomicAdd into out ---
    #pragma unroll
    for (int ni = 0; ni < 2; ++ni) {
        const int col = w * 32 + ni * 16 + lo;
        const float b2v = b2[e * D_DIM + col];
        #pragma unroll
        for (int mi = 0; mi < 4; ++mi) {
            #pragma unroll
            for (int rg = 0; rg < 4; ++rg) {
                const int r = mi * 16 + hi * 4 + rg;
                if (r < nval) {
                    const float v = (acc2[mi][ni][rg] + b2v) * wts[r];
                    atomicAdd(&out[(size_t)toks[r] * D_DIM + col], v);
                }
            }
        }
    }
}

// ---------------------------------------------------------------------------
extern "C" void kernel_launch(void* const* d_in, const int* in_sizes, int n_in,
                              void* d_out, int out_size, void* d_ws, size_t ws_size,
                              hipStream_t stream) {
    const float* x      = (const float*)d_in[0];
    const float* gate_w = (const float*)d_in[1];
    const float* gate_b = (const float*)d_in[2];
    const float* W1     = (const float*)d_in[3];
    const float* b1     = (const float*)d_in[4];
    const float* W2     = (const float*)d_in[5];
    const float* b2     = (const float*)d_in[6];
    float* out = (float*)d_out;

    char* ws = (char*)d_ws;
    ushort* xb      = (ushort*)(ws);                        // 33,554,432 B
    ushort* W1p     = (ushort*)(ws + 33554432);             //  2,097,152 B
    ushort* W2p     = (ushort*)(ws + 35651584);             //  2,097,152 B
    int*    idx_lst = (int*)   (ws + 37748736);             //  2,097,152 B
    float*  wt_lst  = (float*) (ws + 39845888);             //  2,097,152 B
    int*    counts  = (int*)   (ws + 41943040);             //         32 B
    int*    tiles   = (int*)   (ws + 41943104);             //      8,320 B
    int*    n_tiles = (int*)   (ws + 41951424);             //          4 B

    hipMemsetAsync(counts, 0, 32, stream);
    hipMemsetAsync(d_out, 0, (size_t)out_size * sizeof(float), stream);

    pack_w<<<dim3(512, 2), 256, 0, stream>>>(W1, W2, W1p, W2p);
    gating<<<dim3(1024), 256, 0, stream>>>(x, gate_w, gate_b, xb, counts, idx_lst, wt_lst);
    make_tiles<<<dim3(1), 256, 0, stream>>>(counts, tiles, n_tiles);
    moe_expert<<<dim3(GRID_TILES), 512, 0, stream>>>(xb, W1p, W2p, b1, b2, counts,
                                                     idx_lst, wt_lst, tiles, n_tiles, out);
}

// Round 4
// 221.123 us; speedup vs baseline: 1.3446x; 1.0316x over previous
//
#include <hip/hip_runtime.h>
#include <hip/hip_bf16.h>
#include <math.h>

// SwitchMoE: B=16,T=4096,D=256,H=512,E=8, top-2 routing.
// Sparse (top-2 only) bf16-MFMA implementation, fp64 gating for tie-exactness.
// R4: 32-row tiles (48 acc regs -> 4 waves/SIMD), in-kernel tile resolve,
//     s_setprio around MFMA clusters.

#define N_TOK 65536
#define D_DIM 256
#define H_DIM 512
#define E_NUM 8
#define TILE_R 32
#define GRID_TILES 4104   // >= 4096+7 worst-case tiles, multiple of 8

typedef __bf16 bf16x8 __attribute__((ext_vector_type(8)));
typedef float f32x4 __attribute__((ext_vector_type(4)));

static __device__ __forceinline__ ushort f2bf(float f) {
    __hip_bfloat16 h = __float2bfloat16(f);  // RNE
    ushort u;
    __builtin_memcpy(&u, &h, 2);
    return u;
}

// Branch-free GeLU, exact-erf via A&S 7.1.26 3-term (|err|<=2.5e-5).
static __device__ __forceinline__ float gelu(float v) {
    const float a = fabsf(v) * 0.70710678118654752f;
    const float t = __builtin_amdgcn_rcpf(fmaf(a, 0.47047f, 1.0f));
    const float p = t * fmaf(t, fmaf(t, 0.7478556f, -0.0958798f), 0.3480242f);
    const float er = fmaf(-p, __expf(-a * a), 1.0f);   // erf(a), a>=0
    const float s = copysignf(er, v);
    return 0.5f * v * (1.0f + s);
}

// ---------------------------------------------------------------------------
// Pack W1/W2 fp32 -> bf16 in MFMA-fragment-major layout.
// W1p: [e][nb=H/16][kb=D/32][lane=64][j=8]  (value = W1[e][kb*32+(l>>4)*8+j][nb*16+(l&15)])
// W2p: [e][nb=D/16][kb=H/32][lane=64][j=8]
// ---------------------------------------------------------------------------
__global__ __launch_bounds__(256) void pack_w(const float* __restrict__ W1,
                                              const float* __restrict__ W2,
                                              ushort* __restrict__ W1p,
                                              ushort* __restrict__ W2p) {
    const int t = blockIdx.x * 256 + threadIdx.x;   // 0..131071
    const int l = t & 63;
    const int lo = l & 15, hi = l >> 4;
    ushort v[8];
    if (blockIdx.y == 0) {
        const int kb = (t >> 6) & 7;
        const int nb = (t >> 9) & 31;
        const int e  = t >> 14;
        const int k0 = kb * 32 + hi * 8;
        const int n  = nb * 16 + lo;
        const float* src = W1 + (size_t)e * D_DIM * H_DIM + n;
        #pragma unroll
        for (int j = 0; j < 8; ++j)
            v[j] = f2bf(src[(size_t)(k0 + j) * H_DIM]);
        *(uint4*)(W1p + (size_t)t * 8) = *(const uint4*)v;
    } else {
        const int kb = (t >> 6) & 15;
        const int nb = (t >> 10) & 15;
        const int e  = t >> 14;
        const int k0 = kb * 32 + hi * 8;
        const int n  = nb * 16 + lo;
        const float* src = W2 + (size_t)e * H_DIM * D_DIM + n;
        #pragma unroll
        for (int j = 0; j < 8; ++j)
            v[j] = f2bf(src[(size_t)(k0 + j) * D_DIM]);
        *(uint4*)(W2p + (size_t)t * 8) = *(const uint4*)v;
    }
}

// ---------------------------------------------------------------------------
// Gating: convert x -> bf16 (ws), fp64 logits, softmax, top-2, expert lists.
// ---------------------------------------------------------------------------
__global__ __launch_bounds__(256) void gating(const float* __restrict__ x,
                                              const float* __restrict__ gate_w,
                                              const float* __restrict__ gate_b,
                                              ushort* __restrict__ xb,
                                              int* __restrict__ counts,
                                              int* __restrict__ idx_list,
                                              float* __restrict__ wt_list) {
    __shared__ float gws[2048];
    __shared__ int lc[8];
    __shared__ int lbase[8];

    const int tid = threadIdx.x;
    const size_t t0 = (size_t)blockIdx.x * 64;

    for (int i = tid; i < 2048; i += 256) gws[i] = gate_w[i];
    if (tid < 8) lc[tid] = 0;
    __syncthreads();

    const int m = tid >> 2, q = tid & 3;               // token m, quarter q
    const float4* xr = (const float4*)(x + (t0 + m) * D_DIM + q * 64);
    ushort4* xw = (ushort4*)(xb + (t0 + m) * D_DIM + q * 64);

    double lg[8] = {0, 0, 0, 0, 0, 0, 0, 0};
    #pragma unroll
    for (int it = 0; it < 16; ++it) {
        const float4 v = xr[it];
        ushort4 bv;
        bv.x = f2bf(v.x); bv.y = f2bf(v.y); bv.z = f2bf(v.z); bv.w = f2bf(v.w);
        xw[it] = bv;
        const float* g = &gws[(q * 64 + it * 4) * 8];
        const float vv[4] = {v.x, v.y, v.z, v.w};
        #pragma unroll
        for (int j = 0; j < 4; ++j) {
            const double xv = (double)vv[j];
            #pragma unroll
            for (int e2 = 0; e2 < 8; ++e2) lg[e2] += xv * (double)g[j * 8 + e2];
        }
    }
    #pragma unroll
    for (int e2 = 0; e2 < 8; ++e2) {
        lg[e2] += __shfl_xor(lg[e2], 1, 64);
        lg[e2] += __shfl_xor(lg[e2], 2, 64);
    }

    int e0 = 0, e1 = 0, lp0 = 0, lp1 = 0;
    float p0 = 0.f, p1 = 0.f;
    if (q == 0) {
        #pragma unroll
        for (int e2 = 0; e2 < 8; ++e2) lg[e2] += (double)gate_b[e2];
        double b0 = -1e300, b1v = -1e300;
        #pragma unroll
        for (int e2 = 0; e2 < 8; ++e2)
            if (lg[e2] > b0) { b0 = lg[e2]; e0 = e2; }
        e1 = -1;
        #pragma unroll
        for (int e2 = 0; e2 < 8; ++e2)
            if (e2 != e0 && lg[e2] > b1v) { b1v = lg[e2]; e1 = e2; }
        double s = 0;
        #pragma unroll
        for (int e2 = 0; e2 < 8; ++e2) s += exp(lg[e2] - b0);
        p0 = (float)(1.0 / s);
        p1 = (float)(exp(b1v - b0) / s);
        lp0 = atomicAdd(&lc[e0], 1);
        lp1 = atomicAdd(&lc[e1], 1);
    }
    __syncthreads();
    if (tid < 8) lbase[tid] = atomicAdd(&counts[tid], lc[tid]);
    __syncthreads();
    if (q == 0) {
        const int tok = (int)t0 + m;
        const int o0 = e0 * N_TOK + lbase[e0] + lp0;
        idx_list[o0] = tok; wt_list[o0] = p0;
        const int o1 = e1 * N_TOK + lbase[e1] + lp1;
        idx_list[o1] = tok; wt_list[o1] = p1;
    }
}

// ---------------------------------------------------------------------------
// Expert kernel: one 32-row tile per block. 512 threads (8 waves).
// Tile (expert,row0) resolved in-kernel from counts prefix scan.
// GEMM1 (swapped: A=W1p,B=X) -> GeLU -> H(LDS bf16) -> GEMM2 -> atomicAdd.
// Xs (16KB) overlaid inside Hs (32KB) union -> ~33KB LDS.
// acc regs: 32+16 -> combined reg footprint ~110 -> 4 waves/SIMD.
// ---------------------------------------------------------------------------
__global__ __launch_bounds__(512, 4) void moe_expert(const ushort* __restrict__ xb,
                                                     const ushort* __restrict__ W1p,
                                                     const ushort* __restrict__ W2p,
                                                     const float* __restrict__ b1,
                                                     const float* __restrict__ b2,
                                                     const int* __restrict__ counts,
                                                     const int* __restrict__ idx_list,
                                                     const float* __restrict__ wt_list,
                                                     float* __restrict__ out) {
    __shared__ __align__(16) char U[TILE_R * 1024];   // Hs[32][1024B]; Xs[32][512B] overlaid
    __shared__ int toks[TILE_R];
    __shared__ float wts[TILE_R];

    const int bid = blockIdx.x;
    const int wg = (bid & 7) * (GRID_TILES / 8) + (bid >> 3);   // bijective XCD chunking

    // resolve (expert, row0) from counts prefix scan (uniform, 8 entries)
    int e = -1, row0 = 0, cnt = 0, s = 0;
    #pragma unroll
    for (int i = 0; i < 8; ++i) {
        const int c = counts[i];
        const int nt = (c + TILE_R - 1) >> 5;
        if (e < 0 && wg < s + nt) { e = i; row0 = (wg - s) << 5; cnt = c; }
        s += nt;
    }
    if (e < 0) return;
    const int nval = min(TILE_R, cnt - row0);
    const int tid = threadIdx.x;

    char* Xs = U;
    char* Hs = U;

    const int w = tid >> 6;          // wave 0..7
    const int l = tid & 63;
    const int lo = l & 15, hi = l >> 4;

    if (tid < TILE_R) {
        const bool vld = tid < nval;
        toks[tid] = vld ? idx_list[e * N_TOK + row0 + tid] : 0;
        wts[tid]  = vld ? wt_list[e * N_TOK + row0 + tid] : 0.0f;
    }

    // --- prefetch W1 ks=0 fragments (independent of toks) ---
    const char* w1b = (const char*)W1p + (size_t)(e * 32 + w * 4) * 8192 + (size_t)l * 16;
    bf16x8 wf[2][4];
    #pragma unroll
    for (int nb = 0; nb < 4; ++nb)
        wf[0][nb] = *(const bf16x8*)(w1b + nb * 8192);

    __syncthreads();

    // --- stage gathered X rows (bf16) into swizzled LDS: 16 thr/row, 32B each ---
    {
        const int r = tid >> 4, sb = (tid & 15) * 32;
        const char* src = (const char*)(xb + (size_t)toks[r] * D_DIM);
        char* dst = Xs + r * 512;
        const int sw = (r & 7) << 4;
        *(uint4*)(dst + (sb ^ sw)) = *(const uint4*)(src + sb);
        *(uint4*)(dst + ((sb + 16) ^ sw)) = *(const uint4*)(src + sb + 16);
    }
    __syncthreads();

    // --- GEMM1 (swapped): acc1[nb][tb] = sum_k W1[k][hcol] * X[tok][k] ---
    f32x4 acc1[4][2];
    #pragma unroll
    for (int nb = 0; nb < 4; ++nb)
        #pragma unroll
        for (int tb = 0; tb < 2; ++tb)
            acc1[nb][tb] = (f32x4){0.f, 0.f, 0.f, 0.f};

    #pragma unroll
    for (int ks = 0; ks < 8; ++ks) {
        const int cur = ks & 1, nxt = cur ^ 1;
        if (ks < 7) {
            #pragma unroll
            for (int nb = 0; nb < 4; ++nb)
                wf[nxt][nb] = *(const bf16x8*)(w1b + nb * 8192 + (ks + 1) * 1024);
        }
        #pragma unroll
        for (int tb = 0; tb < 2; ++tb) {
            const int slot = tb * 16 + lo;
            const bf16x8 xf = *(const bf16x8*)(Xs + slot * 512 +
                              ((ks * 64 + hi * 16) ^ ((slot & 7) << 4)));
            __builtin_amdgcn_s_setprio(1);
            #pragma unroll
            for (int nb = 0; nb < 4; ++nb)
                acc1[nb][tb] = __builtin_amdgcn_mfma_f32_16x16x32_bf16(wf[cur][nb], xf, acc1[nb][tb], 0, 0, 0);
            __builtin_amdgcn_s_setprio(0);
        }
    }

    // --- prefetch W2 ks=0 fragments before the GeLU phase ---
    const char* w2b = (const char*)W2p + (size_t)(e * 16 + w * 2) * 16384 + (size_t)l * 16;
    bf16x8 wf2[2][2];
    wf2[0][0] = *(const bf16x8*)(w2b);
    wf2[0][1] = *(const bf16x8*)(w2b + 16384);

    __syncthreads();   // all waves done reading Xs before H overwrites the union

    // --- bias + GeLU -> bf16 H (vectorized b64 stores, 4 hcols per lane) ---
    #pragma unroll
    for (int nb = 0; nb < 4; ++nb) {
        const int hc0 = w * 64 + nb * 16 + hi * 4;
        const float4 b1q = *(const float4*)(b1 + e * H_DIM + hc0);
        #pragma unroll
        for (int tb = 0; tb < 2; ++tb) {
            const int slot = tb * 16 + lo;
            ushort4 hv;
            hv.x = f2bf(gelu(acc1[nb][tb][0] + b1q.x));
            hv.y = f2bf(gelu(acc1[nb][tb][1] + b1q.y));
            hv.z = f2bf(gelu(acc1[nb][tb][2] + b1q.z));
            hv.w = f2bf(gelu(acc1[nb][tb][3] + b1q.w));
            *(ushort4*)(Hs + slot * 1024 + ((hc0 * 2) ^ ((slot & 7) << 4))) = hv;
        }
    }
    __syncthreads();

    // --- GEMM2: acc2[mi][ni], A=H rows, B=W2p, double-buffered W2 frags ---
    f32x4 acc2[2][2];
    #pragma unroll
    for (int mi = 0; mi < 2; ++mi)
        #pragma unroll
        for (int ni = 0; ni < 2; ++ni)
            acc2[mi][ni] = (f32x4){0.f, 0.f, 0.f, 0.f};

    #pragma unroll
    for (int ks = 0; ks < 16; ++ks) {
        const int cur = ks & 1, nxt = cur ^ 1;
        if (ks < 15) {
            wf2[nxt][0] = *(const bf16x8*)(w2b + (ks + 1) * 1024);
            wf2[nxt][1] = *(const bf16x8*)(w2b + 16384 + (ks + 1) * 1024);
        }
        #pragma unroll
        for (int mi = 0; mi < 2; ++mi) {
            const int slot = mi * 16 + lo;
            const bf16x8 hf = *(const bf16x8*)(Hs + slot * 1024 +
                              ((ks * 64 + hi * 16) ^ ((slot & 7) << 4)));
            __builtin_amdgcn_s_setprio(1);
            #pragma unroll
            for (int ni = 0; ni < 2; ++ni)
                acc2[mi][ni] = __builtin_amdgcn_mfma_f32_16x16x32_bf16(hf, wf2[cur][ni], acc2[mi][ni], 0, 0, 0);
            __builtin_amdgcn_s_setprio(0);
        }
    }

    // --- epilogue: (y + b2) * weight, atomicAdd into out ---
    #pragma unroll
    for (int ni = 0; ni < 2; ++ni) {
        const int col = w * 32 + ni * 16 + lo;
        const float b2v = b2[e * D_DIM + col];
        #pragma unroll
        for (int mi = 0; mi < 2; ++mi) {
            #pragma unroll
            for (int rg = 0; rg < 4; ++rg) {
                const int r = mi * 16 + hi * 4 + rg;
                if (r < nval) {
                    const float v = (acc2[mi][ni][rg] + b2v) * wts[r];
                    atomicAdd(&out[(size_t)toks[r] * D_DIM + col], v);
                }
            }
        }
    }
}

// ---------------------------------------------------------------------------
extern "C" void kernel_launch(void* const* d_in, const int* in_sizes, int n_in,
                              void* d_out, int out_size, void* d_ws, size_t ws_size,
                              hipStream_t stream) {
    const float* x      = (const float*)d_in[0];
    const float* gate_w = (const float*)d_in[1];
    const float* gate_b = (const float*)d_in[2];
    const float* W1     = (const float*)d_in[3];
    const float* b1     = (const float*)d_in[4];
    const float* W2     = (const float*)d_in[5];
    const float* b2     = (const float*)d_in[6];
    float* out = (float*)d_out;

    char* ws = (char*)d_ws;
    ushort* xb      = (ushort*)(ws);                        // 33,554,432 B
    ushort* W1p     = (ushort*)(ws + 33554432);             //  2,097,152 B
    ushort* W2p     = (ushort*)(ws + 35651584);             //  2,097,152 B
    int*    idx_lst = (int*)   (ws + 37748736);             //  2,097,152 B
    float*  wt_lst  = (float*) (ws + 39845888);             //  2,097,152 B
    int*    counts  = (int*)   (ws + 41943040);             //         32 B

    hipMemsetAsync(counts, 0, 32, stream);
    hipMemsetAsync(d_out, 0, (size_t)out_size * sizeof(float), stream);

    pack_w<<<dim3(512, 2), 256, 0, stream>>>(W1, W2, W1p, W2p);
    gating<<<dim3(1024), 256, 0, stream>>>(x, gate_w, gate_b, xb, counts, idx_lst, wt_lst);
    moe_expert<<<dim3(GRID_TILES), 512, 0, stream>>>(xb, W1p, W2p, b1, b2, counts,
                                                     idx_lst, wt_lst, out);
}